// Round 4
// baseline (4829.394 us; speedup 1.0000x reference)
//
#include <hip/hip_runtime.h>

// Problem dims (fixed)
#define BATCH 32
#define SEQ   512
#define DMOD  1024
#define DFFN  4096
#define NHEAD 16
#define DHEAD 64
#define NLAY  4
#define NTOK  (BATCH * SEQ)   // 16384

typedef __attribute__((ext_vector_type(8))) short short8;
typedef __attribute__((ext_vector_type(4))) float f32x4;
typedef unsigned int uint32;

__device__ __forceinline__ unsigned short f2bf(float f) {
  uint32 u = __builtin_bit_cast(uint32, f);
  u += 0x7fffu + ((u >> 16) & 1u);             // RNE
  return (unsigned short)(u >> 16);
}
__device__ __forceinline__ float gelu_f(float x) {
  float u = 0.7978845608028654f * (x + 0.044715f * x * x * x);
  u = fminf(fmaxf(u, -15.f), 15.f);
  float e = __expf(2.f * u);
  return 0.5f * x * (1.f + (e - 1.f) / (e + 1.f));
}

#define GLOAD16(g, l) __builtin_amdgcn_global_load_lds( \
    (const __attribute__((address_space(1))) void*)(g), \
    (__attribute__((address_space(3))) void*)(l), 16, 0, 0)

#define MFMA16(a, b, c) __builtin_amdgcn_mfma_f32_16x16x32_bf16((a), (b), (c), 0, 0, 0)

// ---------------- positional encoding table: pe[l][d], 512x1024 ----------------
__global__ __launch_bounds__(256) void pe_kernel(float* __restrict__ pe) {
  const int idx = blockIdx.x * 256 + threadIdx.x;   // 0 .. 512*512-1 (pairs)
  const int l = idx >> 9;
  const int i = idx & 511;
  const float dv = __expf((float)(2 * i) * (-9.210340371976184f / (float)DMOD));
  const float a = (float)l * dv;
  pe[(size_t)l * DMOD + 2 * i]     = sinf(a);
  pe[(size_t)l * DMOD + 2 * i + 1] = cosf(a);
}

// ---------------- x + pe + speaker -> (optional f32) + bf16 ----------------
__global__ __launch_bounds__(256) void prep_kernel(
    const float* __restrict__ x, const float* __restrict__ pe, const float* __restrict__ spk,
    float* __restrict__ of32, unsigned short* __restrict__ o16)
{
  const size_t id4 = (size_t)blockIdx.x * 256 + threadIdx.x;  // over B*L*D/4
  const size_t e = id4 * 4;
  const int b  = (int)(e >> 19);                 // / (512*1024)
  const int ld = (int)(e & ((1u << 19) - 1));    // l*1024 + d
  const int d  = (int)(e & 1023);
  float4 xv = ((const float4*)x)[id4];
  float4 pv = ((const float4*)pe)[ld >> 2];
  float4 sv = ((const float4*)spk)[(size_t)b * 256 + (d >> 2)];
  float4 o;
  o.x = xv.x + pv.x + sv.x;
  o.y = xv.y + pv.y + sv.y;
  o.z = xv.z + pv.z + sv.z;
  o.w = xv.w + pv.w + sv.w;
  if (of32) ((float4*)of32)[id4] = o;
  ushort4 h;
  h.x = f2bf(o.x); h.y = f2bf(o.y); h.z = f2bf(o.z); h.w = f2bf(o.w);
  ((ushort4*)o16)[id4] = h;
}

// ---------------- weight transpose+cast: W[K][N] f32 -> Wt[N][K] bf16 ----------------
__global__ __launch_bounds__(256) void wtrans_kernel(
    const float* __restrict__ W, unsigned short* __restrict__ Wt, int K, int N)
{
  __shared__ float tile[64][65];
  const int n0 = blockIdx.x * 64, k0 = blockIdx.y * 64;
  const int tx = threadIdx.x & 63, ty = threadIdx.x >> 6;
  #pragma unroll
  for (int i = 0; i < 16; i++) {
    int r = ty + 4 * i;
    tile[r][tx] = W[(size_t)(k0 + r) * N + n0 + tx];
  }
  __syncthreads();
  #pragma unroll
  for (int i = 0; i < 16; i++) {
    int rn = ty + 4 * i;
    Wt[(size_t)(n0 + rn) * K + k0 + tx] = f2bf(tile[tx][rn]);
  }
}

// ---------------- LayerNorm: one block per row (1024 cols) ----------------
template<int WRITE_F32>
__global__ __launch_bounds__(256) void ln_kernel(
    const float* __restrict__ x, const float* __restrict__ g, const float* __restrict__ bta,
    float* __restrict__ of32, unsigned short* __restrict__ o16)
{
  const int row = blockIdx.x;
  const int t = threadIdx.x;
  const float4 v = ((const float4*)(x + (size_t)row * DMOD))[t];
  float s  = v.x + v.y + v.z + v.w;
  float s2 = v.x*v.x + v.y*v.y + v.z*v.z + v.w*v.w;
  #pragma unroll
  for (int off = 32; off > 0; off >>= 1) {
    s  += __shfl_down(s, off);
    s2 += __shfl_down(s2, off);
  }
  __shared__ float red[8];
  if ((t & 63) == 0) { red[(t >> 6) * 2] = s; red[(t >> 6) * 2 + 1] = s2; }
  __syncthreads();
  const float sum  = red[0] + red[2] + red[4] + red[6];
  const float sum2 = red[1] + red[3] + red[5] + red[7];
  const float mean = sum * (1.f / (float)DMOD);
  const float var  = sum2 * (1.f / (float)DMOD) - mean * mean;
  const float rstd = rsqrtf(var + 1e-6f);
  const float4 gg = ((const float4*)g)[t];
  const float4 bb = ((const float4*)bta)[t];
  float4 o;
  o.x = (v.x - mean) * rstd * gg.x + bb.x;
  o.y = (v.y - mean) * rstd * gg.y + bb.y;
  o.z = (v.z - mean) * rstd * gg.z + bb.z;
  o.w = (v.w - mean) * rstd * gg.w + bb.w;
  if (WRITE_F32) ((float4*)of32)[(size_t)row * 256 + t] = o;
  ushort4 h;
  h.x = f2bf(o.x); h.y = f2bf(o.y); h.z = f2bf(o.z); h.w = f2bf(o.w);
  ((ushort4*)o16)[(size_t)row * 256 + t] = h;
}

// ---------------- GEMM 256x256, 8 waves, ring-4 K-32 pipeline, counted vmcnt --------
// C = A(MxK,bf16) * Bt(NxK,bf16)^T + bias
// EPI: 0 = bias -> bf16 ; 1 = bias+gelu -> bf16 ;
//      2 = bias + res(f32, distinct) -> f32 ; 3 = bias + in-place add -> f32 ;
//      4 = bias -> bf16 TRANSPOSED per-head: out[(b*1024+ch)*512 + (tok&511)]
template<int EPI>
__global__ __launch_bounds__(512, 2) void gemm256(
    const unsigned short* __restrict__ A, const unsigned short* __restrict__ Bt,
    const float* __restrict__ bias, const float* __restrict__ res,
    void* outp, int N, int K)
{
  __shared__ unsigned short Asl[4][256 * 32];   // 64 KB (4 ring slots)
  __shared__ unsigned short Bsl[4][256 * 32];   // 64 KB
  const int t = threadIdx.x;
  const int lane = t & 63, w = t >> 6;
  const int wm = w >> 2, wn = w & 3;            // 2 x 4 wave grid
  const int g = lane >> 4, rm = lane & 15;
  const size_t tm = (size_t)blockIdx.y * 256;
  const size_t tn = (size_t)blockIdx.x * 256;

  // staging: per thread, 2x16B chunks per operand per K-tile (256 rows x 64B)
  const int idx0 = t, idx1 = 512 + t;
  const int ar0 = idx0 >> 2, ac0 = (idx0 & 3) * 8;
  const int ar1 = idx1 >> 2, ac1 = (idx1 & 3) * 8;
  const unsigned short* Abase = A + tm * (size_t)K;
  const unsigned short* Bbase = Bt + tn * (size_t)K;

  auto stage = [&](int kt, int s) {
    const int k0 = kt * 32;
    GLOAD16(Abase + (size_t)ar0 * K + k0 + ac0, &Asl[s][idx0 * 8]);
    GLOAD16(Abase + (size_t)ar1 * K + k0 + ac1, &Asl[s][idx1 * 8]);
    GLOAD16(Bbase + (size_t)ar0 * K + k0 + ac0, &Bsl[s][idx0 * 8]);
    GLOAD16(Bbase + (size_t)ar1 * K + k0 + ac1, &Bsl[s][idx1 * 8]);
  };

  f32x4 acc[8][4];
  #pragma unroll
  for (int i = 0; i < 8; i++)
    #pragma unroll
    for (int j = 0; j < 4; j++)
      acc[i][j] = (f32x4){0.f, 0.f, 0.f, 0.f};

  const int nt = K >> 5;
  stage(0, 0); stage(1, 1); stage(2, 2);        // prefetch depth 3

  for (int kt = 0; kt < nt; kt++) {
    // allow the 2 newest tiles' loads (4 each) to stay in flight across the barrier
    if (kt + 3 <= nt)      asm volatile("s_waitcnt vmcnt(8)" ::: "memory");
    else if (kt + 2 <= nt) asm volatile("s_waitcnt vmcnt(4)" ::: "memory");
    else                   asm volatile("s_waitcnt vmcnt(0)" ::: "memory");
    __builtin_amdgcn_s_barrier();
    asm volatile("" ::: "memory");              // fence: no LDS reads above barrier
    const int s = kt & 3;
    if (kt + 3 < nt) stage(kt + 3, (kt + 3) & 3);   // into slot freed by this barrier

    short8 bfr[4], afr[8];
    #pragma unroll
    for (int fn = 0; fn < 4; fn++)
      bfr[fn] = *(const short8*)&Bsl[s][(wn * 64 + fn * 16 + rm) * 32 + g * 8];
    #pragma unroll
    for (int fm = 0; fm < 8; fm++)
      afr[fm] = *(const short8*)&Asl[s][(wm * 128 + fm * 16 + rm) * 32 + g * 8];

    __builtin_amdgcn_s_setprio(1);
    #pragma unroll
    for (int fm = 0; fm < 8; fm++)
      #pragma unroll
      for (int fn = 0; fn < 4; fn++)
        acc[fm][fn] = MFMA16(afr[fm], bfr[fn], acc[fm][fn]);
    __builtin_amdgcn_s_setprio(0);
  }

  #pragma unroll
  for (int fn = 0; fn < 4; fn++) {
    const size_t gcol = tn + wn * 64 + fn * 16 + rm;
    const float bc = bias[gcol];
    #pragma unroll
    for (int fm = 0; fm < 8; fm++) {
      #pragma unroll
      for (int r = 0; r < 4; r++) {
        const size_t grow = tm + wm * 128 + fm * 16 + g * 4 + r;
        const size_t off = grow * (size_t)N + gcol;
        float v = acc[fm][fn][r] + bc;
        if (EPI == 0) {
          ((unsigned short*)outp)[off] = f2bf(v);
        } else if (EPI == 1) {
          ((unsigned short*)outp)[off] = f2bf(gelu_f(v));
        } else if (EPI == 2) {
          ((float*)outp)[off] = v + res[off];
        } else if (EPI == 3) {
          float* op = (float*)outp;
          op[off] = v + op[off];
        } else {
          const int tok = (int)grow;
          const int bb = tok >> 9, ll = tok & 511;
          ((unsigned short*)outp)[((size_t)bb * 1024 + gcol) * 512 + ll] = f2bf(v);
        }
      }
    }
  }
}

// ---------------- MFMA flash attention (unchanged from round 3) ----------------
__global__ __launch_bounds__(256) void attn_mfma(
    const unsigned short* __restrict__ qb, const unsigned short* __restrict__ kb,
    const unsigned short* __restrict__ vt, unsigned short* __restrict__ ctx)
{
  __shared__ unsigned short Qs[128 * 64];      // 16 KB
  __shared__ unsigned short Ks[2][32 * 64];    //  8 KB
  __shared__ unsigned short Vs[2][64 * 32];    //  8 KB
  __shared__ unsigned short Ps[4][32 * 40];    // 10 KB
  const int t = threadIdx.x;
  const int lane = t & 63, w = t >> 6;
  const int g = lane >> 4, rm = lane & 15;
  const int qt = blockIdx.x, h = blockIdx.y, b = blockIdx.z;

  const unsigned short* qg = qb + ((size_t)(b * SEQ + qt * 128)) * DMOD + h * DHEAD;
  const unsigned short* kg = kb + ((size_t)(b * SEQ)) * DMOD + h * DHEAD;
  const unsigned short* vg = vt + ((size_t)(b * NHEAD + h)) * DHEAD * SEQ;  // [64][512]

  #pragma unroll
  for (int ii = 0; ii < 4; ii++) {
    const int i = ii * 256 + t;
    const int r = i >> 3, c = i & 7;
    const int bc = 16 * (c ^ (r & 7));
    GLOAD16(qg + (size_t)r * DMOD + (bc >> 1), Qs + (size_t)(ii * 256 + w * 64) * 8);
  }
  __syncthreads();

  short8 aq[2][2];
  #pragma unroll
  for (int fq = 0; fq < 2; fq++)
    #pragma unroll
    for (int kd = 0; kd < 2; kd++) {
      const int r = w * 32 + fq * 16 + rm;
      aq[fq][kd] = *(const short8*)((const char*)Qs + r * 128 + ((kd * 64 + g * 16) ^ ((r & 7) << 4)));
    }

  float mrow[2][4], lrow[2][4];
  f32x4 of[2][4];
  #pragma unroll
  for (int fq = 0; fq < 2; fq++) {
    #pragma unroll
    for (int j = 0; j < 4; j++) { mrow[fq][j] = -INFINITY; lrow[fq][j] = 0.f; }
    #pragma unroll
    for (int fd = 0; fd < 4; fd++) of[fq][fd] = (f32x4){0.f, 0.f, 0.f, 0.f};
  }

  auto stageK = [&](int kt, int bf) {
    const int r = t >> 3, c = t & 7;
    const int bc = 16 * (c ^ (r & 7));
    GLOAD16(kg + (size_t)(kt * 32 + r) * DMOD + (bc >> 1), Ks[bf] + (size_t)w * 512);
  };
  auto stageV = [&](int kt, int bf) {
    const int r = t >> 2, c = t & 3;
    const int bc = 16 * (c ^ (r & 3));
    GLOAD16(vg + (size_t)r * SEQ + kt * 32 + (bc >> 1), Vs[bf] + (size_t)w * 512);
  };

  stageK(0, 0); stageV(0, 0);
  __syncthreads();
  int buf = 0;

  for (int kt = 0; kt < SEQ / 32; kt++) {
    if (kt + 1 < SEQ / 32) { stageK(kt + 1, buf ^ 1); stageV(kt + 1, buf ^ 1); }

    f32x4 s[2][2];
    #pragma unroll
    for (int fq = 0; fq < 2; fq++)
      #pragma unroll
      for (int fk = 0; fk < 2; fk++) {
        f32x4 a = (f32x4){0.f, 0.f, 0.f, 0.f};
        #pragma unroll
        for (int kd = 0; kd < 2; kd++) {
          const int r = fk * 16 + rm;
          short8 bk = *(const short8*)((const char*)Ks[buf] + r * 128 + ((kd * 64 + g * 16) ^ ((r & 7) << 4)));
          a = MFMA16(aq[fq][kd], bk, a);
        }
        s[fq][fk] = a;
      }

    #pragma unroll
    for (int fq = 0; fq < 2; fq++) {
      #pragma unroll
      for (int j = 0; j < 4; j++) {
        const float s0 = s[fq][0][j] * 0.125f;
        const float s1 = s[fq][1][j] * 0.125f;
        float mx = fmaxf(s0, s1);
        #pragma unroll
        for (int mk = 1; mk < 16; mk <<= 1) mx = fmaxf(mx, __shfl_xor(mx, mk));
        const float mo = mrow[fq][j];
        const float mn = fmaxf(mo, mx);
        const float corr = __expf(mo - mn);
        mrow[fq][j] = mn;
        const float p0 = __expf(s0 - mn);
        const float p1 = __expf(s1 - mn);
        float rs = p0 + p1;
        #pragma unroll
        for (int mk = 1; mk < 16; mk <<= 1) rs += __shfl_xor(rs, mk);
        lrow[fq][j] = lrow[fq][j] * corr + rs;
        #pragma unroll
        for (int fd = 0; fd < 4; fd++) of[fq][fd][j] *= corr;
        Ps[w][(fq * 16 + g * 4 + j) * 40 + rm]      = f2bf(p0);
        Ps[w][(fq * 16 + g * 4 + j) * 40 + 16 + rm] = f2bf(p1);
      }
    }

    #pragma unroll
    for (int fq = 0; fq < 2; fq++) {
      const short8 pa = *(const short8*)((const char*)Ps[w] + (fq * 16 + rm) * 80 + g * 16);
      #pragma unroll
      for (int fd = 0; fd < 4; fd++) {
        const int r = fd * 16 + rm;
        const short8 vb = *(const short8*)((const char*)Vs[buf] + r * 64 + ((g * 16) ^ ((r & 3) << 4)));
        of[fq][fd] = MFMA16(pa, vb, of[fq][fd]);
      }
    }

    __syncthreads();
    buf ^= 1;
  }

  #pragma unroll
  for (int fq = 0; fq < 2; fq++)
    #pragma unroll
    for (int j = 0; j < 4; j++) {
      const float inv = 1.f / lrow[fq][j];
      const size_t q = (size_t)b * SEQ + qt * 128 + w * 32 + fq * 16 + g * 4 + j;
      #pragma unroll
      for (int fd = 0; fd < 4; fd++)
        ctx[q * DMOD + h * DHEAD + fd * 16 + rm] = f2bf(of[fq][fd][j] * inv);
    }
}

extern "C" void kernel_launch(void* const* d_in, const int* in_sizes, int n_in,
                              void* d_out, int out_size, void* d_ws, size_t ws_size,
                              hipStream_t stream) {
  const float* x_a   = (const float*)d_in[0];
  const float* x_b   = (const float*)d_in[1];
  const float* spk   = (const float*)d_in[2];
  const float* Wq    = (const float*)d_in[3];
  const float* bq    = (const float*)d_in[4];
  const float* Wk    = (const float*)d_in[5];
  const float* bk    = (const float*)d_in[6];
  const float* Wv    = (const float*)d_in[7];
  const float* bv    = (const float*)d_in[8];
  const float* Wo    = (const float*)d_in[9];
  const float* bo    = (const float*)d_in[10];
  const float* ln_g  = (const float*)d_in[11];
  const float* ln_b  = (const float*)d_in[12];
  const float* fln_g = (const float*)d_in[13];
  const float* fln_b = (const float*)d_in[14];
  const float* W1    = (const float*)d_in[15];
  const float* b1    = (const float*)d_in[16];
  const float* W2    = (const float*)d_in[17];
  const float* b2    = (const float*)d_in[18];
  float* out = (float*)d_out;           // also serves as the f32 x_b master (X)

  char* ws = (char*)d_ws;
  size_t o = 0;
  auto give = [&](size_t bytes) { char* p = ws + o; o += (bytes + 255) & ~(size_t)255; return p; };
  const size_t ACT2 = (size_t)NTOK * DMOD * 2;   // 32 MB bf16 activation

  unsigned short* qb16  = (unsigned short*)give(ACT2);       // also inter lo
  unsigned short* kb16  = (unsigned short*)give(ACT2);       // also inter hi
  unsigned short* vt16  = (unsigned short*)give(ACT2);       // V^T [b][h][d][l]
  unsigned short* xa16  = (unsigned short*)give(ACT2);
  unsigned short* xbn16 = (unsigned short*)give(ACT2);
  unsigned short* ctx16 = (unsigned short*)give(ACT2);
  float*          outf  = (float*)give((size_t)NTOK * DMOD * 4);   // 64 MB (residual stream)
  unsigned short* Wqt   = (unsigned short*)give((size_t)DMOD * DMOD * 2);
  unsigned short* Wkt   = (unsigned short*)give((size_t)DMOD * DMOD * 2);
  unsigned short* Wvt   = (unsigned short*)give((size_t)DMOD * DMOD * 2);
  unsigned short* Wot   = (unsigned short*)give((size_t)DMOD * DMOD * 2);
  unsigned short* W1t   = (unsigned short*)give((size_t)DMOD * DFFN * 2);
  unsigned short* W2t   = (unsigned short*)give((size_t)DMOD * DFFN * 2);
  float*          peb   = (float*)give((size_t)SEQ * DMOD * 4);
  unsigned short* inter = qb16;     // 64 MB span over qb16+kb16 (dead during FFN)
  (void)ws_size; (void)in_sizes; (void)n_in; (void)out_size;

  const dim3 blk(256);
  const dim3 blk512(512);

  pe_kernel<<<dim3((SEQ * (DMOD / 2)) / 256), blk, 0, stream>>>(peb);
  const int nprep = (NTOK * DMOD / 4) / 256;
  prep_kernel<<<dim3(nprep), blk, 0, stream>>>(x_a, peb, spk, nullptr, xa16);
  prep_kernel<<<dim3(nprep), blk, 0, stream>>>(x_b, peb, spk, out, xbn16);

  const dim3 g1024(DMOD / 256, NTOK / 256);   // (4,64) = 256 blocks
  const int  MCH = NTOK / 2;                  // FFN token-chunk (8192 rows)

  for (int i = 0; i < NLAY; i++) {
    const size_t wo = (size_t)i * DMOD * DMOD;
    const size_t wf = (size_t)i * DMOD * DFFN;
    wtrans_kernel<<<dim3(16, 16), blk, 0, stream>>>(Wq + wo, Wqt, DMOD, DMOD);
    wtrans_kernel<<<dim3(16, 16), blk, 0, stream>>>(Wk + wo, Wkt, DMOD, DMOD);
    wtrans_kernel<<<dim3(16, 16), blk, 0, stream>>>(Wv + wo, Wvt, DMOD, DMOD);
    wtrans_kernel<<<dim3(16, 16), blk, 0, stream>>>(Wo + wo, Wot, DMOD, DMOD);
    wtrans_kernel<<<dim3(64, 16), blk, 0, stream>>>(W1 + wf, W1t, DMOD, DFFN);
    wtrans_kernel<<<dim3(16, 64), blk, 0, stream>>>(W2 + wf, W2t, DFFN, DMOD);

    if (i != 0) {
      ln_kernel<1><<<dim3(NTOK), blk, 0, stream>>>(out, ln_g + (size_t)i * DMOD, ln_b + (size_t)i * DMOD, outf, xbn16);
    }
    gemm256<0><<<g1024, blk512, 0, stream>>>(xbn16, Wqt, bq + (size_t)i * DMOD, nullptr, qb16, DMOD, DMOD);
    gemm256<0><<<g1024, blk512, 0, stream>>>(xa16,  Wkt, bk + (size_t)i * DMOD, nullptr, kb16, DMOD, DMOD);
    gemm256<4><<<g1024, blk512, 0, stream>>>(xa16,  Wvt, bv + (size_t)i * DMOD, nullptr, vt16, DMOD, DMOD);
    attn_mfma<<<dim3(SEQ / 128, NHEAD, BATCH), blk, 0, stream>>>(qb16, kb16, vt16, ctx16);
    if (i == 0) {
      gemm256<2><<<g1024, blk512, 0, stream>>>(ctx16, Wot, bo + (size_t)i * DMOD, out, outf, DMOD, DMOD);
    } else {
      gemm256<3><<<g1024, blk512, 0, stream>>>(ctx16, Wot, bo + (size_t)i * DMOD, nullptr, outf, DMOD, DMOD);
    }
    ln_kernel<0><<<dim3(NTOK), blk, 0, stream>>>(outf, fln_g + (size_t)i * DMOD, fln_b + (size_t)i * DMOD, nullptr, xbn16);
    for (int c = 0; c < 2; c++) {
      const size_t moff = (size_t)c * MCH;
      gemm256<1><<<dim3(DFFN / 256, MCH / 256), blk512, 0, stream>>>(
          xbn16 + moff * DMOD, W1t, b1 + (size_t)i * DFFN, nullptr, inter, DFFN, DMOD);
      gemm256<2><<<dim3(DMOD / 256, MCH / 256), blk512, 0, stream>>>(
          inter, W2t, b2 + (size_t)i * DMOD, outf + moff * DMOD, out + moff * DMOD, DMOD, DFFN);
    }
  }
}

// Round 5
// 3997.956 us; speedup vs baseline: 1.2080x; 1.2080x over previous
//
#include <hip/hip_runtime.h>

// Problem dims (fixed)
#define BATCH 32
#define SEQ   512
#define DMOD  1024
#define DFFN  4096
#define NHEAD 16
#define DHEAD 64
#define NLAY  4
#define NTOK  (BATCH * SEQ)   // 16384

typedef __attribute__((ext_vector_type(8))) short short8;
typedef __attribute__((ext_vector_type(4))) float f32x4;
typedef unsigned int uint32;

__device__ __forceinline__ unsigned short f2bf(float f) {
  uint32 u = __builtin_bit_cast(uint32, f);
  u += 0x7fffu + ((u >> 16) & 1u);             // RNE
  return (unsigned short)(u >> 16);
}
__device__ __forceinline__ float gelu_f(float x) {
  float u = 0.7978845608028654f * (x + 0.044715f * x * x * x);
  u = fminf(fmaxf(u, -15.f), 15.f);
  float e = __expf(2.f * u);
  return 0.5f * x * (1.f + (e - 1.f) / (e + 1.f));
}

#define GLOAD16(g, l) __builtin_amdgcn_global_load_lds( \
    (const __attribute__((address_space(1))) void*)(g), \
    (__attribute__((address_space(3))) void*)(l), 16, 0, 0)

#define MFMA16(a, b, c) __builtin_amdgcn_mfma_f32_16x16x32_bf16((a), (b), (c), 0, 0, 0)

// ---------------- positional encoding table: pe[l][d], 512x1024 ----------------
__global__ __launch_bounds__(256) void pe_kernel(float* __restrict__ pe) {
  const int idx = blockIdx.x * 256 + threadIdx.x;   // 0 .. 512*512-1 (pairs)
  const int l = idx >> 9;
  const int i = idx & 511;
  const float dv = __expf((float)(2 * i) * (-9.210340371976184f / (float)DMOD));
  const float a = (float)l * dv;
  pe[(size_t)l * DMOD + 2 * i]     = sinf(a);
  pe[(size_t)l * DMOD + 2 * i + 1] = cosf(a);
}

// ---------------- x + pe + speaker -> (optional f32) + bf16 ----------------
__global__ __launch_bounds__(256) void prep_kernel(
    const float* __restrict__ x, const float* __restrict__ pe, const float* __restrict__ spk,
    float* __restrict__ of32, unsigned short* __restrict__ o16)
{
  const size_t id4 = (size_t)blockIdx.x * 256 + threadIdx.x;  // over B*L*D/4
  const size_t e = id4 * 4;
  const int b  = (int)(e >> 19);                 // / (512*1024)
  const int ld = (int)(e & ((1u << 19) - 1));    // l*1024 + d
  const int d  = (int)(e & 1023);
  float4 xv = ((const float4*)x)[id4];
  float4 pv = ((const float4*)pe)[ld >> 2];
  float4 sv = ((const float4*)spk)[(size_t)b * 256 + (d >> 2)];
  float4 o;
  o.x = xv.x + pv.x + sv.x;
  o.y = xv.y + pv.y + sv.y;
  o.z = xv.z + pv.z + sv.z;
  o.w = xv.w + pv.w + sv.w;
  if (of32) ((float4*)of32)[id4] = o;
  ushort4 h;
  h.x = f2bf(o.x); h.y = f2bf(o.y); h.z = f2bf(o.z); h.w = f2bf(o.w);
  ((ushort4*)o16)[id4] = h;
}

// ---------------- weight transpose+cast: W[K][N] f32 -> Wt[N][K] bf16 ----------------
__global__ __launch_bounds__(256) void wtrans_kernel(
    const float* __restrict__ W, unsigned short* __restrict__ Wt, int K, int N)
{
  __shared__ float tile[64][65];
  const int n0 = blockIdx.x * 64, k0 = blockIdx.y * 64;
  const int tx = threadIdx.x & 63, ty = threadIdx.x >> 6;
  #pragma unroll
  for (int i = 0; i < 16; i++) {
    int r = ty + 4 * i;
    tile[r][tx] = W[(size_t)(k0 + r) * N + n0 + tx];
  }
  __syncthreads();
  #pragma unroll
  for (int i = 0; i < 16; i++) {
    int rn = ty + 4 * i;
    Wt[(size_t)(n0 + rn) * K + k0 + tx] = f2bf(tile[tx][rn]);
  }
}

// ---------------- LayerNorm: one block per row (1024 cols) ----------------
template<int WRITE_F32>
__global__ __launch_bounds__(256) void ln_kernel(
    const float* __restrict__ x, const float* __restrict__ g, const float* __restrict__ bta,
    float* __restrict__ of32, unsigned short* __restrict__ o16)
{
  const int row = blockIdx.x;
  const int t = threadIdx.x;
  const float4 v = ((const float4*)(x + (size_t)row * DMOD))[t];
  float s  = v.x + v.y + v.z + v.w;
  float s2 = v.x*v.x + v.y*v.y + v.z*v.z + v.w*v.w;
  #pragma unroll
  for (int off = 32; off > 0; off >>= 1) {
    s  += __shfl_down(s, off);
    s2 += __shfl_down(s2, off);
  }
  __shared__ float red[8];
  if ((t & 63) == 0) { red[(t >> 6) * 2] = s; red[(t >> 6) * 2 + 1] = s2; }
  __syncthreads();
  const float sum  = red[0] + red[2] + red[4] + red[6];
  const float sum2 = red[1] + red[3] + red[5] + red[7];
  const float mean = sum * (1.f / (float)DMOD);
  const float var  = sum2 * (1.f / (float)DMOD) - mean * mean;
  const float rstd = rsqrtf(var + 1e-6f);
  const float4 gg = ((const float4*)g)[t];
  const float4 bb = ((const float4*)bta)[t];
  float4 o;
  o.x = (v.x - mean) * rstd * gg.x + bb.x;
  o.y = (v.y - mean) * rstd * gg.y + bb.y;
  o.z = (v.z - mean) * rstd * gg.z + bb.z;
  o.w = (v.w - mean) * rstd * gg.w + bb.w;
  if (WRITE_F32) ((float4*)of32)[(size_t)row * 256 + t] = o;
  ushort4 h;
  h.x = f2bf(o.x); h.y = f2bf(o.y); h.z = f2bf(o.z); h.w = f2bf(o.w);
  ((ushort4*)o16)[(size_t)row * 256 + t] = h;
}

// ---------------- GEMM 256x256, 8 waves, ring-4 K-32 pipeline, counted vmcnt --------
// LDS bank-swizzle: chunk position sc holds global chunk sc ^ ((row>>1)&3); gload_lds
// dest stays LINEAR, source pre-swizzled, read swizzled (rule 21). 2-way banks = free.
// XCD-aware bijective block remap (grids used are %8 == 0).
// EPI: 0 = bias -> bf16 ; 1 = bias+gelu -> bf16 ;
//      2 = bias + res(f32, distinct) -> f32 ; 3 = bias + in-place add -> f32 ;
//      4 = bias -> bf16 TRANSPOSED per-head: out[(b*1024+ch)*512 + (tok&511)]
template<int EPI>
__global__ __launch_bounds__(512, 2) void gemm256(
    const unsigned short* __restrict__ A, const unsigned short* __restrict__ Bt,
    const float* __restrict__ bias, const float* __restrict__ res,
    void* outp, int N, int K)
{
  __shared__ unsigned short Asl[4][256 * 32];   // 64 KB (4 ring slots)
  __shared__ unsigned short Bsl[4][256 * 32];   // 64 KB
  const int t = threadIdx.x;
  const int lane = t & 63, w = t >> 6;
  const int wm = w >> 2, wn = w & 3;            // 2 x 4 wave grid
  const int g = lane >> 4, rm = lane & 15;

  // XCD-aware remap: same-XCD blocks get contiguous work ids
  const int nwg = gridDim.x * gridDim.y;
  const int hid = blockIdx.y * gridDim.x + blockIdx.x;
  const int wid = (hid & 7) * (nwg >> 3) + (hid >> 3);
  const int bx = wid % gridDim.x, by = wid / gridDim.x;
  const size_t tm = (size_t)by * 256;
  const size_t tn = (size_t)bx * 256;

  // staging: per thread, 2x16B chunks per operand per K-tile (256 rows x 64B)
  // LDS dest linear at chunk idx; source column pre-swizzled.
  const int idx0 = t, idx1 = 512 + t;
  const int ar0 = idx0 >> 2, ar1 = idx1 >> 2;
  const int ac0 = 8 * ((idx0 & 3) ^ ((ar0 >> 1) & 3));
  const int ac1 = 8 * ((idx1 & 3) ^ ((ar1 >> 1) & 3));
  const unsigned short* Abase = A + tm * (size_t)K;
  const unsigned short* Bbase = Bt + tn * (size_t)K;

  auto stage = [&](int kt, int s) {
    const int k0 = kt * 32;
    GLOAD16(Abase + (size_t)ar0 * K + k0 + ac0, &Asl[s][idx0 * 8]);
    GLOAD16(Abase + (size_t)ar1 * K + k0 + ac1, &Asl[s][idx1 * 8]);
    GLOAD16(Bbase + (size_t)ar0 * K + k0 + ac0, &Bsl[s][idx0 * 8]);
    GLOAD16(Bbase + (size_t)ar1 * K + k0 + ac1, &Bsl[s][idx1 * 8]);
  };

  // swizzled read offsets (halfword units) — k-invariant, hoisted
  int aoff[8], boff[4];
  #pragma unroll
  for (int fm = 0; fm < 8; fm++) {
    const int r = wm * 128 + fm * 16 + rm;
    aoff[fm] = r * 32 + 8 * (g ^ ((r >> 1) & 3));
  }
  #pragma unroll
  for (int fn = 0; fn < 4; fn++) {
    const int r = wn * 64 + fn * 16 + rm;
    boff[fn] = r * 32 + 8 * (g ^ ((r >> 1) & 3));
  }

  f32x4 acc[8][4];
  #pragma unroll
  for (int i = 0; i < 8; i++)
    #pragma unroll
    for (int j = 0; j < 4; j++)
      acc[i][j] = (f32x4){0.f, 0.f, 0.f, 0.f};

  const int nt = K >> 5;
  stage(0, 0); stage(1, 1); stage(2, 2);        // prefetch depth 3

  for (int kt = 0; kt < nt; kt++) {
    // keep the 2 newest tiles' loads (4 each) in flight across the barrier
    if (kt + 3 <= nt)      asm volatile("s_waitcnt vmcnt(8)" ::: "memory");
    else if (kt + 2 <= nt) asm volatile("s_waitcnt vmcnt(4)" ::: "memory");
    else                   asm volatile("s_waitcnt vmcnt(0)" ::: "memory");
    __builtin_amdgcn_s_barrier();
    asm volatile("" ::: "memory");              // fence: no LDS reads above barrier
    const int s = kt & 3;
    if (kt + 3 < nt) stage(kt + 3, (kt + 3) & 3);   // into slot freed by this barrier

    short8 bfr[4], afr[8];
    #pragma unroll
    for (int fn = 0; fn < 4; fn++)
      bfr[fn] = *(const short8*)&Bsl[s][boff[fn]];
    #pragma unroll
    for (int fm = 0; fm < 8; fm++)
      afr[fm] = *(const short8*)&Asl[s][aoff[fm]];

    __builtin_amdgcn_s_setprio(1);
    #pragma unroll
    for (int fm = 0; fm < 8; fm++)
      #pragma unroll
      for (int fn = 0; fn < 4; fn++)
        acc[fm][fn] = MFMA16(afr[fm], bfr[fn], acc[fm][fn]);
    __builtin_amdgcn_s_setprio(0);
  }

  #pragma unroll
  for (int fn = 0; fn < 4; fn++) {
    const size_t gcol = tn + wn * 64 + fn * 16 + rm;
    const float bc = bias[gcol];
    #pragma unroll
    for (int fm = 0; fm < 8; fm++) {
      #pragma unroll
      for (int r = 0; r < 4; r++) {
        const size_t grow = tm + wm * 128 + fm * 16 + g * 4 + r;
        const size_t off = grow * (size_t)N + gcol;
        float v = acc[fm][fn][r] + bc;
        if (EPI == 0) {
          ((unsigned short*)outp)[off] = f2bf(v);
        } else if (EPI == 1) {
          ((unsigned short*)outp)[off] = f2bf(gelu_f(v));
        } else if (EPI == 2) {
          ((float*)outp)[off] = v + res[off];
        } else if (EPI == 3) {
          float* op = (float*)outp;
          op[off] = v + op[off];
        } else {
          const int tok = (int)grow;
          const int bb = tok >> 9, ll = tok & 511;
          ((unsigned short*)outp)[((size_t)bb * 1024 + gcol) * 512 + ll] = f2bf(v);
        }
      }
    }
  }
}

// ---------------- MFMA flash attention (unchanged from round 3) ----------------
__global__ __launch_bounds__(256) void attn_mfma(
    const unsigned short* __restrict__ qb, const unsigned short* __restrict__ kb,
    const unsigned short* __restrict__ vt, unsigned short* __restrict__ ctx)
{
  __shared__ unsigned short Qs[128 * 64];      // 16 KB
  __shared__ unsigned short Ks[2][32 * 64];    //  8 KB
  __shared__ unsigned short Vs[2][64 * 32];    //  8 KB
  __shared__ unsigned short Ps[4][32 * 40];    // 10 KB
  const int t = threadIdx.x;
  const int lane = t & 63, w = t >> 6;
  const int g = lane >> 4, rm = lane & 15;
  const int qt = blockIdx.x, h = blockIdx.y, b = blockIdx.z;

  const unsigned short* qg = qb + ((size_t)(b * SEQ + qt * 128)) * DMOD + h * DHEAD;
  const unsigned short* kg = kb + ((size_t)(b * SEQ)) * DMOD + h * DHEAD;
  const unsigned short* vg = vt + ((size_t)(b * NHEAD + h)) * DHEAD * SEQ;  // [64][512]

  #pragma unroll
  for (int ii = 0; ii < 4; ii++) {
    const int i = ii * 256 + t;
    const int r = i >> 3, c = i & 7;
    const int bc = 16 * (c ^ (r & 7));
    GLOAD16(qg + (size_t)r * DMOD + (bc >> 1), Qs + (size_t)(ii * 256 + w * 64) * 8);
  }
  __syncthreads();

  short8 aq[2][2];
  #pragma unroll
  for (int fq = 0; fq < 2; fq++)
    #pragma unroll
    for (int kd = 0; kd < 2; kd++) {
      const int r = w * 32 + fq * 16 + rm;
      aq[fq][kd] = *(const short8*)((const char*)Qs + r * 128 + ((kd * 64 + g * 16) ^ ((r & 7) << 4)));
    }

  float mrow[2][4], lrow[2][4];
  f32x4 of[2][4];
  #pragma unroll
  for (int fq = 0; fq < 2; fq++) {
    #pragma unroll
    for (int j = 0; j < 4; j++) { mrow[fq][j] = -INFINITY; lrow[fq][j] = 0.f; }
    #pragma unroll
    for (int fd = 0; fd < 4; fd++) of[fq][fd] = (f32x4){0.f, 0.f, 0.f, 0.f};
  }

  auto stageK = [&](int kt, int bf) {
    const int r = t >> 3, c = t & 7;
    const int bc = 16 * (c ^ (r & 7));
    GLOAD16(kg + (size_t)(kt * 32 + r) * DMOD + (bc >> 1), Ks[bf] + (size_t)w * 512);
  };
  auto stageV = [&](int kt, int bf) {
    const int r = t >> 2, c = t & 3;
    const int bc = 16 * (c ^ (r & 3));
    GLOAD16(vg + (size_t)r * SEQ + kt * 32 + (bc >> 1), Vs[bf] + (size_t)w * 512);
  };

  stageK(0, 0); stageV(0, 0);
  __syncthreads();
  int buf = 0;

  for (int kt = 0; kt < SEQ / 32; kt++) {
    if (kt + 1 < SEQ / 32) { stageK(kt + 1, buf ^ 1); stageV(kt + 1, buf ^ 1); }

    f32x4 s[2][2];
    #pragma unroll
    for (int fq = 0; fq < 2; fq++)
      #pragma unroll
      for (int fk = 0; fk < 2; fk++) {
        f32x4 a = (f32x4){0.f, 0.f, 0.f, 0.f};
        #pragma unroll
        for (int kd = 0; kd < 2; kd++) {
          const int r = fk * 16 + rm;
          short8 bk = *(const short8*)((const char*)Ks[buf] + r * 128 + ((kd * 64 + g * 16) ^ ((r & 7) << 4)));
          a = MFMA16(aq[fq][kd], bk, a);
        }
        s[fq][fk] = a;
      }

    #pragma unroll
    for (int fq = 0; fq < 2; fq++) {
      #pragma unroll
      for (int j = 0; j < 4; j++) {
        const float s0 = s[fq][0][j] * 0.125f;
        const float s1 = s[fq][1][j] * 0.125f;
        float mx = fmaxf(s0, s1);
        #pragma unroll
        for (int mk = 1; mk < 16; mk <<= 1) mx = fmaxf(mx, __shfl_xor(mx, mk));
        const float mo = mrow[fq][j];
        const float mn = fmaxf(mo, mx);
        const float corr = __expf(mo - mn);
        mrow[fq][j] = mn;
        const float p0 = __expf(s0 - mn);
        const float p1 = __expf(s1 - mn);
        float rs = p0 + p1;
        #pragma unroll
        for (int mk = 1; mk < 16; mk <<= 1) rs += __shfl_xor(rs, mk);
        lrow[fq][j] = lrow[fq][j] * corr + rs;
        #pragma unroll
        for (int fd = 0; fd < 4; fd++) of[fq][fd][j] *= corr;
        Ps[w][(fq * 16 + g * 4 + j) * 40 + rm]      = f2bf(p0);
        Ps[w][(fq * 16 + g * 4 + j) * 40 + 16 + rm] = f2bf(p1);
      }
    }

    #pragma unroll
    for (int fq = 0; fq < 2; fq++) {
      const short8 pa = *(const short8*)((const char*)Ps[w] + (fq * 16 + rm) * 80 + g * 16);
      #pragma unroll
      for (int fd = 0; fd < 4; fd++) {
        const int r = fd * 16 + rm;
        const short8 vb = *(const short8*)((const char*)Vs[buf] + r * 64 + ((g * 16) ^ ((r & 3) << 4)));
        of[fq][fd] = MFMA16(pa, vb, of[fq][fd]);
      }
    }

    __syncthreads();
    buf ^= 1;
  }

  #pragma unroll
  for (int fq = 0; fq < 2; fq++)
    #pragma unroll
    for (int j = 0; j < 4; j++) {
      const float inv = 1.f / lrow[fq][j];
      const size_t q = (size_t)b * SEQ + qt * 128 + w * 32 + fq * 16 + g * 4 + j;
      #pragma unroll
      for (int fd = 0; fd < 4; fd++)
        ctx[q * DMOD + h * DHEAD + fd * 16 + rm] = f2bf(of[fq][fd][j] * inv);
    }
}

extern "C" void kernel_launch(void* const* d_in, const int* in_sizes, int n_in,
                              void* d_out, int out_size, void* d_ws, size_t ws_size,
                              hipStream_t stream) {
  const float* x_a   = (const float*)d_in[0];
  const float* x_b   = (const float*)d_in[1];
  const float* spk   = (const float*)d_in[2];
  const float* Wq    = (const float*)d_in[3];
  const float* bq    = (const float*)d_in[4];
  const float* Wk    = (const float*)d_in[5];
  const float* bk    = (const float*)d_in[6];
  const float* Wv    = (const float*)d_in[7];
  const float* bv    = (const float*)d_in[8];
  const float* Wo    = (const float*)d_in[9];
  const float* bo    = (const float*)d_in[10];
  const float* ln_g  = (const float*)d_in[11];
  const float* ln_b  = (const float*)d_in[12];
  const float* fln_g = (const float*)d_in[13];
  const float* fln_b = (const float*)d_in[14];
  const float* W1    = (const float*)d_in[15];
  const float* b1    = (const float*)d_in[16];
  const float* W2    = (const float*)d_in[17];
  const float* b2    = (const float*)d_in[18];
  float* out = (float*)d_out;           // also serves as the f32 x_b master (X)

  char* ws = (char*)d_ws;
  size_t o = 0;
  auto give = [&](size_t bytes) { char* p = ws + o; o += (bytes + 255) & ~(size_t)255; return p; };
  const size_t ACT2 = (size_t)NTOK * DMOD * 2;   // 32 MB bf16 activation

  // order matters: qb,kb,vt,ctx are contiguous (128 MB) and all dead during FFN,
  // so `inter` (16384 x 4096 bf16 = 128 MB) aliases their span.
  unsigned short* qb16  = (unsigned short*)give(ACT2);
  unsigned short* kb16  = (unsigned short*)give(ACT2);
  unsigned short* vt16  = (unsigned short*)give(ACT2);       // V^T [b][h][d][l]
  unsigned short* ctx16 = (unsigned short*)give(ACT2);
  unsigned short* xa16  = (unsigned short*)give(ACT2);
  unsigned short* xbn16 = (unsigned short*)give(ACT2);
  float*          outf  = (float*)give((size_t)NTOK * DMOD * 4);   // 64 MB (residual stream)
  unsigned short* Wqt   = (unsigned short*)give((size_t)DMOD * DMOD * 2);
  unsigned short* Wkt   = (unsigned short*)give((size_t)DMOD * DMOD * 2);
  unsigned short* Wvt   = (unsigned short*)give((size_t)DMOD * DMOD * 2);
  unsigned short* Wot   = (unsigned short*)give((size_t)DMOD * DMOD * 2);
  unsigned short* W1t   = (unsigned short*)give((size_t)DMOD * DFFN * 2);
  unsigned short* W2t   = (unsigned short*)give((size_t)DMOD * DFFN * 2);
  float*          peb   = (float*)give((size_t)SEQ * DMOD * 4);
  unsigned short* inter = qb16;     // 128 MB span over qb16..ctx16
  (void)ws_size; (void)in_sizes; (void)n_in; (void)out_size;

  const dim3 blk(256);
  const dim3 blk512(512);

  pe_kernel<<<dim3((SEQ * (DMOD / 2)) / 256), blk, 0, stream>>>(peb);
  const int nprep = (NTOK * DMOD / 4) / 256;
  prep_kernel<<<dim3(nprep), blk, 0, stream>>>(x_a, peb, spk, nullptr, xa16);
  prep_kernel<<<dim3(nprep), blk, 0, stream>>>(x_b, peb, spk, out, xbn16);

  const dim3 g1024(DMOD / 256, NTOK / 256);   // (4,64) = 256 blocks
  const dim3 gW1(DFFN / 256, NTOK / 256);     // (16,64) = 1024 blocks
  const dim3 gW2(DMOD / 256, NTOK / 256);     // (4,64) = 256 blocks

  for (int i = 0; i < NLAY; i++) {
    const size_t wo = (size_t)i * DMOD * DMOD;
    const size_t wf = (size_t)i * DMOD * DFFN;
    wtrans_kernel<<<dim3(16, 16), blk, 0, stream>>>(Wq + wo, Wqt, DMOD, DMOD);
    wtrans_kernel<<<dim3(16, 16), blk, 0, stream>>>(Wk + wo, Wkt, DMOD, DMOD);
    wtrans_kernel<<<dim3(16, 16), blk, 0, stream>>>(Wv + wo, Wvt, DMOD, DMOD);
    wtrans_kernel<<<dim3(16, 16), blk, 0, stream>>>(Wo + wo, Wot, DMOD, DMOD);
    wtrans_kernel<<<dim3(64, 16), blk, 0, stream>>>(W1 + wf, W1t, DMOD, DFFN);
    wtrans_kernel<<<dim3(16, 64), blk, 0, stream>>>(W2 + wf, W2t, DFFN, DMOD);

    if (i != 0) {
      ln_kernel<1><<<dim3(NTOK), blk, 0, stream>>>(out, ln_g + (size_t)i * DMOD, ln_b + (size_t)i * DMOD, outf, xbn16);
    }
    gemm256<0><<<g1024, blk512, 0, stream>>>(xbn16, Wqt, bq + (size_t)i * DMOD, nullptr, qb16, DMOD, DMOD);
    gemm256<0><<<g1024, blk512, 0, stream>>>(xa16,  Wkt, bk + (size_t)i * DMOD, nullptr, kb16, DMOD, DMOD);
    gemm256<4><<<g1024, blk512, 0, stream>>>(xa16,  Wvt, bv + (size_t)i * DMOD, nullptr, vt16, DMOD, DMOD);
    attn_mfma<<<dim3(SEQ / 128, NHEAD, BATCH), blk, 0, stream>>>(qb16, kb16, vt16, ctx16);
    if (i == 0) {
      gemm256<2><<<g1024, blk512, 0, stream>>>(ctx16, Wot, bo + (size_t)i * DMOD, out, outf, DMOD, DMOD);
    } else {
      gemm256<3><<<g1024, blk512, 0, stream>>>(ctx16, Wot, bo + (size_t)i * DMOD, nullptr, outf, DMOD, DMOD);
    }
    ln_kernel<0><<<dim3(NTOK), blk, 0, stream>>>(outf, fln_g + (size_t)i * DMOD, fln_b + (size_t)i * DMOD, nullptr, xbn16);
    gemm256<1><<<gW1, blk512, 0, stream>>>(xbn16, W1t, b1 + (size_t)i * DFFN, nullptr, inter, DFFN, DMOD);
    gemm256<2><<<gW2, blk512, 0, stream>>>(inter, W2t, b2 + (size_t)i * DMOD, outf, out, DMOD, DFFN);
  }
}

// Round 6
// 3463.408 us; speedup vs baseline: 1.3944x; 1.1543x over previous
//
#include <hip/hip_runtime.h>

// Problem dims (fixed)
#define BATCH 32
#define SEQ   512
#define DMOD  1024
#define DFFN  4096
#define NHEAD 16
#define DHEAD 64
#define NLAY  4
#define NTOK  (BATCH * SEQ)   // 16384

typedef __attribute__((ext_vector_type(8))) short short8;
typedef __attribute__((ext_vector_type(4))) float f32x4;
typedef unsigned int uint32;

__device__ __forceinline__ unsigned short f2bf(float f) {
  uint32 u = __builtin_bit_cast(uint32, f);
  u += 0x7fffu + ((u >> 16) & 1u);             // RNE
  return (unsigned short)(u >> 16);
}
__device__ __forceinline__ float gelu_f(float x) {
  float u = 0.7978845608028654f * (x + 0.044715f * x * x * x);
  u = fminf(fmaxf(u, -15.f), 15.f);
  float e = __expf(2.f * u);
  return 0.5f * x * (1.f + (e - 1.f) / (e + 1.f));
}

#define GLOAD16(g, l) __builtin_amdgcn_global_load_lds( \
    (const __attribute__((address_space(1))) void*)(g), \
    (__attribute__((address_space(3))) void*)(l), 16, 0, 0)

#define MFMA16(a, b, c) __builtin_amdgcn_mfma_f32_16x16x32_bf16((a), (b), (c), 0, 0, 0)

// ---------------- positional encoding table: pe[l][d], 512x1024 ----------------
__global__ __launch_bounds__(256) void pe_kernel(float* __restrict__ pe) {
  const int idx = blockIdx.x * 256 + threadIdx.x;   // 0 .. 512*512-1 (pairs)
  const int l = idx >> 9;
  const int i = idx & 511;
  const float dv = __expf((float)(2 * i) * (-9.210340371976184f / (float)DMOD));
  const float a = (float)l * dv;
  pe[(size_t)l * DMOD + 2 * i]     = sinf(a);
  pe[(size_t)l * DMOD + 2 * i + 1] = cosf(a);
}

// ---------------- x + pe + speaker -> (optional f32) + bf16 ----------------
__global__ __launch_bounds__(256) void prep_kernel(
    const float* __restrict__ x, const float* __restrict__ pe, const float* __restrict__ spk,
    float* __restrict__ of32, unsigned short* __restrict__ o16)
{
  const size_t id4 = (size_t)blockIdx.x * 256 + threadIdx.x;  // over B*L*D/4
  const size_t e = id4 * 4;
  const int b  = (int)(e >> 19);                 // / (512*1024)
  const int ld = (int)(e & ((1u << 19) - 1));    // l*1024 + d
  const int d  = (int)(e & 1023);
  float4 xv = ((const float4*)x)[id4];
  float4 pv = ((const float4*)pe)[ld >> 2];
  float4 sv = ((const float4*)spk)[(size_t)b * 256 + (d >> 2)];
  float4 o;
  o.x = xv.x + pv.x + sv.x;
  o.y = xv.y + pv.y + sv.y;
  o.z = xv.z + pv.z + sv.z;
  o.w = xv.w + pv.w + sv.w;
  if (of32) ((float4*)of32)[id4] = o;
  ushort4 h;
  h.x = f2bf(o.x); h.y = f2bf(o.y); h.z = f2bf(o.z); h.w = f2bf(o.w);
  ((ushort4*)o16)[id4] = h;
}

// ---------------- weight transpose+cast: W[K][N] f32 -> Wt[N][K] bf16 ----------------
__global__ __launch_bounds__(256) void wtrans_kernel(
    const float* __restrict__ W, unsigned short* __restrict__ Wt, int K, int N)
{
  __shared__ float tile[64][65];
  const int n0 = blockIdx.x * 64, k0 = blockIdx.y * 64;
  const int tx = threadIdx.x & 63, ty = threadIdx.x >> 6;
  #pragma unroll
  for (int i = 0; i < 16; i++) {
    int r = ty + 4 * i;
    tile[r][tx] = W[(size_t)(k0 + r) * N + n0 + tx];
  }
  __syncthreads();
  #pragma unroll
  for (int i = 0; i < 16; i++) {
    int rn = ty + 4 * i;
    Wt[(size_t)(n0 + rn) * K + k0 + tx] = f2bf(tile[tx][rn]);
  }
}

// ---------------- LayerNorm: one block per row (1024 cols) ----------------
template<int WRITE_F32>
__global__ __launch_bounds__(256) void ln_kernel(
    const float* __restrict__ x, const float* __restrict__ g, const float* __restrict__ bta,
    float* __restrict__ of32, unsigned short* __restrict__ o16)
{
  const int row = blockIdx.x;
  const int t = threadIdx.x;
  const float4 v = ((const float4*)(x + (size_t)row * DMOD))[t];
  float s  = v.x + v.y + v.z + v.w;
  float s2 = v.x*v.x + v.y*v.y + v.z*v.z + v.w*v.w;
  #pragma unroll
  for (int off = 32; off > 0; off >>= 1) {
    s  += __shfl_down(s, off);
    s2 += __shfl_down(s2, off);
  }
  __shared__ float red[8];
  if ((t & 63) == 0) { red[(t >> 6) * 2] = s; red[(t >> 6) * 2 + 1] = s2; }
  __syncthreads();
  const float sum  = red[0] + red[2] + red[4] + red[6];
  const float sum2 = red[1] + red[3] + red[5] + red[7];
  const float mean = sum * (1.f / (float)DMOD);
  const float var  = sum2 * (1.f / (float)DMOD) - mean * mean;
  const float rstd = rsqrtf(var + 1e-6f);
  const float4 gg = ((const float4*)g)[t];
  const float4 bb = ((const float4*)bta)[t];
  float4 o;
  o.x = (v.x - mean) * rstd * gg.x + bb.x;
  o.y = (v.y - mean) * rstd * gg.y + bb.y;
  o.z = (v.z - mean) * rstd * gg.z + bb.z;
  o.w = (v.w - mean) * rstd * gg.w + bb.w;
  if (WRITE_F32) ((float4*)of32)[(size_t)row * 256 + t] = o;
  ushort4 h;
  h.x = f2bf(o.x); h.y = f2bf(o.y); h.z = f2bf(o.z); h.w = f2bf(o.w);
  ((ushort4*)o16)[(size_t)row * 256 + t] = h;
}

// ---------------- GEMM 256x256, 8 waves, 8-phase pipelined (m201-style) --------
// LDS: A[2buf][2ks][256 rows][32 k] (64B rows, swizzle c^((row>>1)&3) -> 0 conflicts,
// verified round 5). 4 phases per K-tile (BK=64): quadrant = (ks, N-half).
// Stage slots: P1->B.ks1(t+1), P2->A.ks0(t+2), P3->B.ks0(t+2), P4->A.ks1(t+2)
// (each slot re-staged one phase after its last read, barrier in between).
// vmcnt(6) once per K-tile at P4 confirms ALL of tile t+1 (issue-order ledger).
// EPI: 0 = bias -> bf16 ; 1 = bias+gelu -> bf16 ;
//      2 = bias + res(f32, distinct) -> f32 ; 3 = bias + in-place add -> f32 ;
//      4 = bias -> bf16 TRANSPOSED per-head: out[(b*1024+ch)*512 + (tok&511)]
template<int EPI>
__global__ __launch_bounds__(512, 2) void gemm256(
    const unsigned short* __restrict__ A, const unsigned short* __restrict__ Bt,
    const float* __restrict__ bias, const float* __restrict__ res,
    void* outp, int N, int K)
{
  __shared__ unsigned short Ah[2][2][256 * 32];   // 64 KB
  __shared__ unsigned short Bh[2][2][256 * 32];   // 64 KB
  const int t = threadIdx.x;
  const int lane = t & 63, w = t >> 6;
  const int wm = w >> 2, wn = w & 3;              // 2 x 4 wave grid
  const int g = lane >> 4, rm = lane & 15;

  // XCD-aware bijective remap (all grids used are %8 == 0)
  const int nwg = gridDim.x * gridDim.y;
  const int hid = blockIdx.y * gridDim.x + blockIdx.x;
  const int wid = (hid & 7) * (nwg >> 3) + (hid >> 3);
  const int bx = wid % gridDim.x, by = wid / gridDim.x;
  const size_t tm = (size_t)by * 256;
  const size_t tn = (size_t)bx * 256;

  // staging: per half-tile (256 rows x 32 k = 16 KB), 2 x 16B chunks per thread
  const int i0 = t, i1 = 512 + t;
  const int r0 = i0 >> 2, r1 = i1 >> 2;
  const int sc0 = 8 * ((i0 & 3) ^ ((r0 >> 1) & 3));   // pre-swizzled source col
  const int sc1 = 8 * ((i1 & 3) ^ ((r1 >> 1) & 3));
  const unsigned short* Abase = A + tm * (size_t)K;
  const unsigned short* Bbase = Bt + tn * (size_t)K;

  auto stA = [&](int kt, int ks, int bf) {
    const int k0 = kt * 64 + ks * 32;
    GLOAD16(Abase + (size_t)r0 * K + k0 + sc0, &Ah[bf][ks][i0 * 8]);
    GLOAD16(Abase + (size_t)r1 * K + k0 + sc1, &Ah[bf][ks][i1 * 8]);
  };
  auto stB = [&](int kt, int ks, int bf) {
    const int k0 = kt * 64 + ks * 32;
    GLOAD16(Bbase + (size_t)r0 * K + k0 + sc0, &Bh[bf][ks][i0 * 8]);
    GLOAD16(Bbase + (size_t)r1 * K + k0 + sc1, &Bh[bf][ks][i1 * 8]);
  };

  // swizzled fragment read offsets (bytes within a half) — k-invariant
  int aoff[8], boff[4];
  #pragma unroll
  for (int fm = 0; fm < 8; fm++) {
    const int r = wm * 128 + fm * 16 + rm;
    aoff[fm] = r * 64 + ((g * 16) ^ (((r >> 1) & 3) << 4));
  }
  #pragma unroll
  for (int fn = 0; fn < 4; fn++) {
    const int r = wn * 64 + fn * 16 + rm;
    boff[fn] = r * 64 + ((g * 16) ^ (((r >> 1) & 3) << 4));
  }

  f32x4 acc[8][4];
  #pragma unroll
  for (int i = 0; i < 8; i++)
    #pragma unroll
    for (int j = 0; j < 4; j++)
      acc[i][j] = (f32x4){0.f, 0.f, 0.f, 0.f};

  const int nt = K >> 6;   // BK = 64
  // prologue: tile0 full + {Aks0,Bks0,Aks1}(1); Bks1(1) comes at P1(0)
  stA(0, 0, 0); stB(0, 0, 0); stA(0, 1, 0); stB(0, 1, 0);
  stA(1, 0, 1); stB(1, 0, 1); stA(1, 1, 1);
  asm volatile("s_waitcnt vmcnt(6)" ::: "memory");
  __builtin_amdgcn_s_barrier();

  for (int kt = 0; kt < nt; kt++) {
    const int bf = kt & 1;
    const char* pA0 = (const char*)Ah[bf][0];
    const char* pA1 = (const char*)Ah[bf][1];
    const char* pB0 = (const char*)Bh[bf][0];
    const char* pB1 = (const char*)Bh[bf][1];
    short8 a[8], bA, bB;

    // ---- P1: A.ks0 + B[n0..1, ks0]; MFMA quadrant (ks0, n-half0) ----
    #pragma unroll
    for (int fm = 0; fm < 8; fm++) a[fm] = *(const short8*)(pA0 + aoff[fm]);
    bA = *(const short8*)(pB0 + boff[0]);
    bB = *(const short8*)(pB0 + boff[1]);
    if (kt + 1 < nt) stB(kt + 1, 1, bf ^ 1);
    __builtin_amdgcn_s_barrier();
    asm volatile("s_waitcnt lgkmcnt(0)" ::: "memory");
    __builtin_amdgcn_sched_barrier(0);
    __builtin_amdgcn_s_setprio(1);
    #pragma unroll
    for (int fm = 0; fm < 8; fm++) acc[fm][0] = MFMA16(a[fm], bA, acc[fm][0]);
    #pragma unroll
    for (int fm = 0; fm < 8; fm++) acc[fm][1] = MFMA16(a[fm], bB, acc[fm][1]);
    __builtin_amdgcn_s_setprio(0);
    __builtin_amdgcn_s_barrier();

    // ---- P2: B[n2..3, ks0]; quadrant (ks0, n-half1) ----
    bA = *(const short8*)(pB0 + boff[2]);
    bB = *(const short8*)(pB0 + boff[3]);
    if (kt + 2 < nt) stA(kt + 2, 0, bf);
    __builtin_amdgcn_s_barrier();
    asm volatile("s_waitcnt lgkmcnt(0)" ::: "memory");
    __builtin_amdgcn_sched_barrier(0);
    __builtin_amdgcn_s_setprio(1);
    #pragma unroll
    for (int fm = 0; fm < 8; fm++) acc[fm][2] = MFMA16(a[fm], bA, acc[fm][2]);
    #pragma unroll
    for (int fm = 0; fm < 8; fm++) acc[fm][3] = MFMA16(a[fm], bB, acc[fm][3]);
    __builtin_amdgcn_s_setprio(0);
    __builtin_amdgcn_s_barrier();

    // ---- P3: A.ks1 + B[n2..3, ks1]; quadrant (ks1, n-half1) ----
    #pragma unroll
    for (int fm = 0; fm < 8; fm++) a[fm] = *(const short8*)(pA1 + aoff[fm]);
    bA = *(const short8*)(pB1 + boff[2]);
    bB = *(const short8*)(pB1 + boff[3]);
    if (kt + 2 < nt) stB(kt + 2, 0, bf);
    __builtin_amdgcn_s_barrier();
    asm volatile("s_waitcnt lgkmcnt(0)" ::: "memory");
    __builtin_amdgcn_sched_barrier(0);
    __builtin_amdgcn_s_setprio(1);
    #pragma unroll
    for (int fm = 0; fm < 8; fm++) acc[fm][2] = MFMA16(a[fm], bA, acc[fm][2]);
    #pragma unroll
    for (int fm = 0; fm < 8; fm++) acc[fm][3] = MFMA16(a[fm], bB, acc[fm][3]);
    __builtin_amdgcn_s_setprio(0);
    __builtin_amdgcn_s_barrier();

    // ---- P4: B[n0..1, ks1]; quadrant (ks1, n-half0); tile-boundary vmcnt ----
    bA = *(const short8*)(pB1 + boff[0]);
    bB = *(const short8*)(pB1 + boff[1]);
    if (kt + 2 < nt) stA(kt + 2, 1, bf);
    if (kt < nt - 2)       asm volatile("s_waitcnt vmcnt(6)" ::: "memory");
    else if (kt == nt - 2) asm volatile("s_waitcnt vmcnt(0)" ::: "memory");
    __builtin_amdgcn_s_barrier();
    asm volatile("s_waitcnt lgkmcnt(0)" ::: "memory");
    __builtin_amdgcn_sched_barrier(0);
    __builtin_amdgcn_s_setprio(1);
    #pragma unroll
    for (int fm = 0; fm < 8; fm++) acc[fm][0] = MFMA16(a[fm], bA, acc[fm][0]);
    #pragma unroll
    for (int fm = 0; fm < 8; fm++) acc[fm][1] = MFMA16(a[fm], bB, acc[fm][1]);
    __builtin_amdgcn_s_setprio(0);
    __builtin_amdgcn_s_barrier();
  }

  #pragma unroll
  for (int fn = 0; fn < 4; fn++) {
    const size_t gcol = tn + wn * 64 + fn * 16 + rm;
    const float bc = bias[gcol];
    #pragma unroll
    for (int fm = 0; fm < 8; fm++) {
      #pragma unroll
      for (int r = 0; r < 4; r++) {
        const size_t grow = tm + wm * 128 + fm * 16 + g * 4 + r;
        const size_t off = grow * (size_t)N + gcol;
        float v = acc[fm][fn][r] + bc;
        if (EPI == 0) {
          ((unsigned short*)outp)[off] = f2bf(v);
        } else if (EPI == 1) {
          ((unsigned short*)outp)[off] = f2bf(gelu_f(v));
        } else if (EPI == 2) {
          ((float*)outp)[off] = v + res[off];
        } else if (EPI == 3) {
          float* op = (float*)outp;
          op[off] = v + op[off];
        } else {
          const int tok = (int)grow;
          const int bb = tok >> 9, ll = tok & 511;
          ((unsigned short*)outp)[((size_t)bb * 1024 + gcol) * 512 + ll] = f2bf(v);
        }
      }
    }
  }
}

// ---------------- MFMA flash attention (unchanged from round 3) ----------------
__global__ __launch_bounds__(256) void attn_mfma(
    const unsigned short* __restrict__ qb, const unsigned short* __restrict__ kb,
    const unsigned short* __restrict__ vt, unsigned short* __restrict__ ctx)
{
  __shared__ unsigned short Qs[128 * 64];      // 16 KB
  __shared__ unsigned short Ks[2][32 * 64];    //  8 KB
  __shared__ unsigned short Vs[2][64 * 32];    //  8 KB
  __shared__ unsigned short Ps[4][32 * 40];    // 10 KB
  const int t = threadIdx.x;
  const int lane = t & 63, w = t >> 6;
  const int g = lane >> 4, rm = lane & 15;
  const int qt = blockIdx.x, h = blockIdx.y, b = blockIdx.z;

  const unsigned short* qg = qb + ((size_t)(b * SEQ + qt * 128)) * DMOD + h * DHEAD;
  const unsigned short* kg = kb + ((size_t)(b * SEQ)) * DMOD + h * DHEAD;
  const unsigned short* vg = vt + ((size_t)(b * NHEAD + h)) * DHEAD * SEQ;  // [64][512]

  #pragma unroll
  for (int ii = 0; ii < 4; ii++) {
    const int i = ii * 256 + t;
    const int r = i >> 3, c = i & 7;
    const int bc = 16 * (c ^ (r & 7));
    GLOAD16(qg + (size_t)r * DMOD + (bc >> 1), Qs + (size_t)(ii * 256 + w * 64) * 8);
  }
  __syncthreads();

  short8 aq[2][2];
  #pragma unroll
  for (int fq = 0; fq < 2; fq++)
    #pragma unroll
    for (int kd = 0; kd < 2; kd++) {
      const int r = w * 32 + fq * 16 + rm;
      aq[fq][kd] = *(const short8*)((const char*)Qs + r * 128 + ((kd * 64 + g * 16) ^ ((r & 7) << 4)));
    }

  float mrow[2][4], lrow[2][4];
  f32x4 of[2][4];
  #pragma unroll
  for (int fq = 0; fq < 2; fq++) {
    #pragma unroll
    for (int j = 0; j < 4; j++) { mrow[fq][j] = -INFINITY; lrow[fq][j] = 0.f; }
    #pragma unroll
    for (int fd = 0; fd < 4; fd++) of[fq][fd] = (f32x4){0.f, 0.f, 0.f, 0.f};
  }

  auto stageK = [&](int kt, int bf) {
    const int r = t >> 3, c = t & 7;
    const int bc = 16 * (c ^ (r & 7));
    GLOAD16(kg + (size_t)(kt * 32 + r) * DMOD + (bc >> 1), Ks[bf] + (size_t)w * 512);
  };
  auto stageV = [&](int kt, int bf) {
    const int r = t >> 2, c = t & 3;
    const int bc = 16 * (c ^ (r & 3));
    GLOAD16(vg + (size_t)r * SEQ + kt * 32 + (bc >> 1), Vs[bf] + (size_t)w * 512);
  };

  stageK(0, 0); stageV(0, 0);
  __syncthreads();
  int buf = 0;

  for (int kt = 0; kt < SEQ / 32; kt++) {
    if (kt + 1 < SEQ / 32) { stageK(kt + 1, buf ^ 1); stageV(kt + 1, buf ^ 1); }

    f32x4 s[2][2];
    #pragma unroll
    for (int fq = 0; fq < 2; fq++)
      #pragma unroll
      for (int fk = 0; fk < 2; fk++) {
        f32x4 a = (f32x4){0.f, 0.f, 0.f, 0.f};
        #pragma unroll
        for (int kd = 0; kd < 2; kd++) {
          const int r = fk * 16 + rm;
          short8 bk = *(const short8*)((const char*)Ks[buf] + r * 128 + ((kd * 64 + g * 16) ^ ((r & 7) << 4)));
          a = MFMA16(aq[fq][kd], bk, a);
        }
        s[fq][fk] = a;
      }

    #pragma unroll
    for (int fq = 0; fq < 2; fq++) {
      #pragma unroll
      for (int j = 0; j < 4; j++) {
        const float s0 = s[fq][0][j] * 0.125f;
        const float s1 = s[fq][1][j] * 0.125f;
        float mx = fmaxf(s0, s1);
        #pragma unroll
        for (int mk = 1; mk < 16; mk <<= 1) mx = fmaxf(mx, __shfl_xor(mx, mk));
        const float mo = mrow[fq][j];
        const float mn = fmaxf(mo, mx);
        const float corr = __expf(mo - mn);
        mrow[fq][j] = mn;
        const float p0 = __expf(s0 - mn);
        const float p1 = __expf(s1 - mn);
        float rs = p0 + p1;
        #pragma unroll
        for (int mk = 1; mk < 16; mk <<= 1) rs += __shfl_xor(rs, mk);
        lrow[fq][j] = lrow[fq][j] * corr + rs;
        #pragma unroll
        for (int fd = 0; fd < 4; fd++) of[fq][fd][j] *= corr;
        Ps[w][(fq * 16 + g * 4 + j) * 40 + rm]      = f2bf(p0);
        Ps[w][(fq * 16 + g * 4 + j) * 40 + 16 + rm] = f2bf(p1);
      }
    }

    #pragma unroll
    for (int fq = 0; fq < 2; fq++) {
      const short8 pa = *(const short8*)((const char*)Ps[w] + (fq * 16 + rm) * 80 + g * 16);
      #pragma unroll
      for (int fd = 0; fd < 4; fd++) {
        const int r = fd * 16 + rm;
        const short8 vb = *(const short8*)((const char*)Vs[buf] + r * 64 + ((g * 16) ^ ((r & 3) << 4)));
        of[fq][fd] = MFMA16(pa, vb, of[fq][fd]);
      }
    }

    __syncthreads();
    buf ^= 1;
  }

  #pragma unroll
  for (int fq = 0; fq < 2; fq++)
    #pragma unroll
    for (int j = 0; j < 4; j++) {
      const float inv = 1.f / lrow[fq][j];
      const size_t q = (size_t)b * SEQ + qt * 128 + w * 32 + fq * 16 + g * 4 + j;
      #pragma unroll
      for (int fd = 0; fd < 4; fd++)
        ctx[q * DMOD + h * DHEAD + fd * 16 + rm] = f2bf(of[fq][fd][j] * inv);
    }
}

extern "C" void kernel_launch(void* const* d_in, const int* in_sizes, int n_in,
                              void* d_out, int out_size, void* d_ws, size_t ws_size,
                              hipStream_t stream) {
  const float* x_a   = (const float*)d_in[0];
  const float* x_b   = (const float*)d_in[1];
  const float* spk   = (const float*)d_in[2];
  const float* Wq    = (const float*)d_in[3];
  const float* bq    = (const float*)d_in[4];
  const float* Wk    = (const float*)d_in[5];
  const float* bk    = (const float*)d_in[6];
  const float* Wv    = (const float*)d_in[7];
  const float* bv    = (const float*)d_in[8];
  const float* Wo    = (const float*)d_in[9];
  const float* bo    = (const float*)d_in[10];
  const float* ln_g  = (const float*)d_in[11];
  const float* ln_b  = (const float*)d_in[12];
  const float* fln_g = (const float*)d_in[13];
  const float* fln_b = (const float*)d_in[14];
  const float* W1    = (const float*)d_in[15];
  const float* b1    = (const float*)d_in[16];
  const float* W2    = (const float*)d_in[17];
  const float* b2    = (const float*)d_in[18];
  float* out = (float*)d_out;           // also serves as the f32 x_b master (X)

  char* ws = (char*)d_ws;
  size_t o = 0;
  auto give = [&](size_t bytes) { char* p = ws + o; o += (bytes + 255) & ~(size_t)255; return p; };
  const size_t ACT2 = (size_t)NTOK * DMOD * 2;   // 32 MB bf16 activation

  // qb,kb,vt,ctx contiguous (128 MB), all dead during FFN -> `inter` aliases the span.
  unsigned short* qb16  = (unsigned short*)give(ACT2);
  unsigned short* kb16  = (unsigned short*)give(ACT2);
  unsigned short* vt16  = (unsigned short*)give(ACT2);       // V^T [b][h][d][l]
  unsigned short* ctx16 = (unsigned short*)give(ACT2);
  unsigned short* xa16  = (unsigned short*)give(ACT2);
  unsigned short* xbn16 = (unsigned short*)give(ACT2);
  float*          outf  = (float*)give((size_t)NTOK * DMOD * 4);   // 64 MB (residual stream)
  unsigned short* Wqt   = (unsigned short*)give((size_t)DMOD * DMOD * 2);
  unsigned short* Wkt   = (unsigned short*)give((size_t)DMOD * DMOD * 2);
  unsigned short* Wvt   = (unsigned short*)give((size_t)DMOD * DMOD * 2);
  unsigned short* Wot   = (unsigned short*)give((size_t)DMOD * DMOD * 2);
  unsigned short* W1t   = (unsigned short*)give((size_t)DMOD * DFFN * 2);
  unsigned short* W2t   = (unsigned short*)give((size_t)DMOD * DFFN * 2);
  float*          peb   = (float*)give((size_t)SEQ * DMOD * 4);
  unsigned short* inter = qb16;     // 128 MB span over qb16..ctx16
  (void)ws_size; (void)in_sizes; (void)n_in; (void)out_size;

  const dim3 blk(256);
  const dim3 blk512(512);

  pe_kernel<<<dim3((SEQ * (DMOD / 2)) / 256), blk, 0, stream>>>(peb);
  const int nprep = (NTOK * DMOD / 4) / 256;
  prep_kernel<<<dim3(nprep), blk, 0, stream>>>(x_a, peb, spk, nullptr, xa16);
  prep_kernel<<<dim3(nprep), blk, 0, stream>>>(x_b, peb, spk, out, xbn16);

  const dim3 g1024(DMOD / 256, NTOK / 256);   // (4,64) = 256 blocks
  const dim3 gW1(DFFN / 256, NTOK / 256);     // (16,64) = 1024 blocks
  const dim3 gW2(DMOD / 256, NTOK / 256);     // (4,64) = 256 blocks

  for (int i = 0; i < NLAY; i++) {
    const size_t wo = (size_t)i * DMOD * DMOD;
    const size_t wf = (size_t)i * DMOD * DFFN;
    wtrans_kernel<<<dim3(16, 16), blk, 0, stream>>>(Wq + wo, Wqt, DMOD, DMOD);
    wtrans_kernel<<<dim3(16, 16), blk, 0, stream>>>(Wk + wo, Wkt, DMOD, DMOD);
    wtrans_kernel<<<dim3(16, 16), blk, 0, stream>>>(Wv + wo, Wvt, DMOD, DMOD);
    wtrans_kernel<<<dim3(16, 16), blk, 0, stream>>>(Wo + wo, Wot, DMOD, DMOD);
    wtrans_kernel<<<dim3(64, 16), blk, 0, stream>>>(W1 + wf, W1t, DMOD, DFFN);
    wtrans_kernel<<<dim3(16, 64), blk, 0, stream>>>(W2 + wf, W2t, DFFN, DMOD);

    if (i != 0) {
      ln_kernel<1><<<dim3(NTOK), blk, 0, stream>>>(out, ln_g + (size_t)i * DMOD, ln_b + (size_t)i * DMOD, outf, xbn16);
    }
    gemm256<0><<<g1024, blk512, 0, stream>>>(xbn16, Wqt, bq + (size_t)i * DMOD, nullptr, qb16, DMOD, DMOD);
    gemm256<0><<<g1024, blk512, 0, stream>>>(xa16,  Wkt, bk + (size_t)i * DMOD, nullptr, kb16, DMOD, DMOD);
    gemm256<4><<<g1024, blk512, 0, stream>>>(xa16,  Wvt, bv + (size_t)i * DMOD, nullptr, vt16, DMOD, DMOD);
    attn_mfma<<<dim3(SEQ / 128, NHEAD, BATCH), blk, 0, stream>>>(qb16, kb16, vt16, ctx16);
    if (i == 0) {
      gemm256<2><<<g1024, blk512, 0, stream>>>(ctx16, Wot, bo + (size_t)i * DMOD, out, outf, DMOD, DMOD);
    } else {
      gemm256<3><<<g1024, blk512, 0, stream>>>(ctx16, Wot, bo + (size_t)i * DMOD, nullptr, outf, DMOD, DMOD);
    }
    ln_kernel<0><<<dim3(NTOK), blk, 0, stream>>>(outf, fln_g + (size_t)i * DMOD, fln_b + (size_t)i * DMOD, nullptr, xbn16);
    gemm256<1><<<gW1, blk512, 0, stream>>>(xbn16, W1t, b1 + (size_t)i * DFFN, nullptr, inter, DFFN, DMOD);
    gemm256<2><<<gW2, blk512, 0, stream>>>(inter, W2t, b2 + (size_t)i * DMOD, outf, out, DMOD, DFFN);
  }
}